// Round 1
// baseline (115.451 us; speedup 1.0000x reference)
//
#include <hip/hip_runtime.h>

#define B_ 32
#define C_ 64
#define N_ 2048
#define D_ 6

static __device__ __forceinline__ float2 ld2(const float* p) {
    return *reinterpret_cast<const float2*>(p);
}

// Output layout (flat, return order), all float32:
//  [0]                      log_prob (scalar)
//  [1        .. +B*C*N)     vote_presence (bool as 0/1)
//  [..       .. +B*N*6)     winner
//  [..       .. +B*N)       winner_pres
//  [..       .. +B*N)       is_from_capsule (always 0)
//  [..       .. +B*(C+1)*N) mixing_logits
//  [..       .. +B*(C+1)*N) mixing_log_prob
//  [..       .. +B*N*6)     soft_winner
//  [..       .. +B*N)       soft_winner_pres
//  [..       .. +B*N*C)     posterior_mixing_probs (transposed [B,N,C])
//  [..       .. +B*C)       caps_presence_prob
static constexpr long OFF_VP   = 1;
static constexpr long OFF_WIN  = OFF_VP   + (long)B_*C_*N_;
static constexpr long OFF_WINP = OFF_WIN  + (long)B_*N_*D_;
static constexpr long OFF_IFC  = OFF_WINP + (long)B_*N_;
static constexpr long OFF_ML   = OFF_IFC  + (long)B_*N_;
static constexpr long OFF_MLP  = OFF_ML   + (long)B_*(C_+1)*N_;
static constexpr long OFF_SW   = OFF_MLP  + (long)B_*(C_+1)*N_;
static constexpr long OFF_SWP  = OFF_SW   + (long)B_*N_*D_;
static constexpr long OFF_PMP  = OFF_SWP  + (long)B_*N_;
static constexpr long OFF_CAPS = OFF_PMP  + (long)B_*N_*C_;

__global__ __launch_bounds__(256) void capsule_main(
    const float* __restrict__ x,
    const float* __restrict__ votes,
    const float* __restrict__ scale,
    const float* __restrict__ vpp,
    const float* __restrict__ dummy_vote,
    float* __restrict__ out,
    float* __restrict__ block_sums)
{
    constexpr float DUMMY       = -4.6051702f;   // -2*ln(10)
    constexpr float HALFDLOG2PI =  5.5136312f;   // 0.5*D*ln(2*pi) = 3*ln(2*pi)

    const int tid = threadIdx.x;
    const int idx = blockIdx.x * 256 + tid;      // b*N + n
    const int b   = idx >> 11;                   // N_ == 2048
    const int n   = idx & (N_ - 1);

    // x[b,n,0..5]
    const float* xp = x + (size_t)idx * D_;
    const float2 xa = ld2(xp), xb = ld2(xp + 2), xc = ld2(xp + 4);

    // dummy_vote[0,0,n,0..5]
    const float* dp = dummy_vote + (size_t)n * D_;
    const float2 da = ld2(dp), db = ld2(dp + 2), dc = ld2(dp + 4);

    float post[C_];   // exp(posterior_c), kept in registers (loops fully unrolled)

    // logsumexp(mixing_logits) = log(sum(vpp+eps) + exp(DUMMY)); exp(DUMMY)=0.01
    float s_pp = 0.01f;
    // posterior logsumexp/softmax accumulated without max-shift:
    // dummy entry posterior = 2*DUMMY -> exp = 1e-4 (floors the sum, no overflow/underflow risk)
    float s_p  = 1.0e-4f;
    float sw0 = 1.0e-4f * da.x, sw1 = 1.0e-4f * da.y,
          sw2 = 1.0e-4f * db.x, sw3 = 1.0e-4f * db.y,
          sw4 = 1.0e-4f * dc.x, sw5 = 1.0e-4f * dc.y;
    float swp = 0.0f;                            // dummy presence contributes 0
    float best = -3.4e38f, winp = 0.0f;
    float w0=0.f,w1=0.f,w2=0.f,w3=0.f,w4=0.f,w5=0.f;
    int bc = 0;

    const size_t base  = (size_t)b * (C_ * N_) + n;        // scale/vpp index, c=0
    const float* scp   = scale + base;
    const float* ppp   = vpp + base;
    const float* vb    = votes + base * D_;                // votes index, c=0
    const size_t mlrow = (size_t)b * ((C_ + 1) * N_) + n;  // mixing_logits row base

#pragma unroll
    for (int c = 0; c < C_; ++c) {
        const float* vp = vb + (size_t)c * (N_ * D_);
        const float2 va = ld2(vp), vbb = ld2(vp + 2), vc2 = ld2(vp + 4);
        const float s = scp[(size_t)c * N_];
        const float p = ppp[(size_t)c * N_];
        const float inv = 1.0f / s;
        const float z0 = (xa.x - va.x)  * inv;
        const float z1 = (xa.y - va.y)  * inv;
        const float z2 = (xb.x - vbb.x) * inv;
        const float z3 = (xb.y - vbb.y) * inv;
        const float z4 = (xc.x - vc2.x) * inv;
        const float z5 = (xc.y - vc2.y) * inv;
        float q = z0 * z0;
        q = fmaf(z1, z1, q); q = fmaf(z2, z2, q);
        q = fmaf(z3, z3, q); q = fmaf(z4, z4, q);
        q = fmaf(z5, z5, q);
        const float vlp = fmaf(-0.5f, q, fmaf(-6.0f, __logf(s), -HALFDLOG2PI));
        const float ml  = __logf(p + 1e-16f);
        out[OFF_ML + mlrow + (size_t)c * N_] = ml;         // coalesced over n
        const float pc = ml + vlp;                          // posterior logit
        const float e  = __expf(pc);
        post[c] = e;
        s_pp += p + 1e-16f;
        s_p  += e;
        sw0 = fmaf(e, va.x,  sw0); sw1 = fmaf(e, va.y,  sw1);
        sw2 = fmaf(e, vbb.x, sw2); sw3 = fmaf(e, vbb.y, sw3);
        sw4 = fmaf(e, vc2.x, sw4); sw5 = fmaf(e, vc2.y, sw5);
        swp = fmaf(e, p, swp);
        const bool better = pc > best;                      // strict > keeps first max (jnp.argmax)
        best = better ? pc : best;
        bc   = better ? c  : bc;
        w0 = better ? va.x  : w0; w1 = better ? va.y  : w1;
        w2 = better ? vbb.x : w2; w3 = better ? vbb.y : w3;
        w4 = better ? vc2.x : w4; w5 = better ? vc2.y : w5;
        winp = better ? p : winp;
    }

    const float lse_ml = __logf(s_pp);
    const float lse_p  = __logf(s_p);      // mixture_log_prob_per_point
    const float inv_sp = 1.0f / s_p;

    // dummy rows of mixing_logits / mixing_log_prob
    out[OFF_ML  + mlrow + (size_t)C_ * N_] = DUMMY;
    out[OFF_MLP + mlrow + (size_t)C_ * N_] = DUMMY - lse_ml;

    // per-point outputs
    {
        float* wq = out + OFF_WIN + (size_t)idx * D_;
        wq[0] = w0; wq[1] = w1; wq[2] = w2; wq[3] = w3; wq[4] = w4; wq[5] = w5;
        out[OFF_WINP + idx] = winp;
        out[OFF_IFC + idx]  = (float)(bc / N_);            // always 0 (bc < 64 < 2048)
        float* sq = out + OFF_SW + (size_t)idx * D_;
        sq[0] = sw0 * inv_sp; sq[1] = sw1 * inv_sp; sq[2] = sw2 * inv_sp;
        sq[3] = sw3 * inv_sp; sq[4] = sw4 * inv_sp; sq[5] = sw5 * inv_sp;
        out[OFF_SWP + idx] = swp * inv_sp;
    }

    // pass 2: mixing_log_prob, vote_presence, transposed softmax probs
    float* pmp = out + OFF_PMP + (size_t)idx * C_;
#pragma unroll
    for (int c = 0; c < C_; ++c) {
        const float p  = ppp[(size_t)c * N_];              // L2/L3-hot re-read
        const float ml = __logf(p + 1e-16f);
        out[OFF_MLP + mlrow + (size_t)c * N_] = ml - lse_ml;
        out[OFF_VP + (size_t)(b * C_ + c) * N_ + n] = (DUMMY < ml) ? 1.0f : 0.0f;
        pmp[c] = post[c] * inv_sp;
    }

    // deterministic block-level sum of lse_p for log_prob
    __shared__ float red[256];
    red[tid] = lse_p;
    __syncthreads();
#pragma unroll
    for (int off2 = 128; off2 > 0; off2 >>= 1) {
        if (tid < off2) red[tid] += red[tid + off2];
        __syncthreads();
    }
    if (tid == 0) block_sums[blockIdx.x] = red[0];
}

__global__ __launch_bounds__(256) void capsule_logprob_reduce(
    const float* __restrict__ block_sums, float* __restrict__ out)
{
    __shared__ float red[256];
    const int tid = threadIdx.x;
    red[tid] = block_sums[tid];
    __syncthreads();
#pragma unroll
    for (int off2 = 128; off2 > 0; off2 >>= 1) {
        if (tid < off2) red[tid] += red[tid + off2];
        __syncthreads();
    }
    if (tid == 0) out[0] = red[0] * (1.0f / (float)B_);
}

__global__ __launch_bounds__(256) void capsule_caps_pres(
    const float* __restrict__ vpp, float* __restrict__ out)
{
    const int bcq = blockIdx.x;             // b*C + c
    const int tid = threadIdx.x;
    const float* p = vpp + (size_t)bcq * N_;
    float m = -3.4e38f;
#pragma unroll
    for (int t = 0; t < N_ / 256; ++t)
        m = fmaxf(m, p[t * 256 + tid]);
    __shared__ float red[256];
    red[tid] = m;
    __syncthreads();
#pragma unroll
    for (int off2 = 128; off2 > 0; off2 >>= 1) {
        if (tid < off2) red[tid] = fmaxf(red[tid], red[tid + off2]);
        __syncthreads();
    }
    if (tid == 0) out[OFF_CAPS + bcq] = red[0];
}

extern "C" void kernel_launch(void* const* d_in, const int* in_sizes, int n_in,
                              void* d_out, int out_size, void* d_ws, size_t ws_size,
                              hipStream_t stream) {
    const float* x     = (const float*)d_in[0];
    const float* votes = (const float*)d_in[1];
    const float* scale = (const float*)d_in[2];
    const float* vpp   = (const float*)d_in[3];
    const float* dummy = (const float*)d_in[4];
    float* out = (float*)d_out;
    float* ws  = (float*)d_ws;   // 256 floats of block sums

    capsule_main<<<(B_ * N_) / 256, 256, 0, stream>>>(x, votes, scale, vpp, dummy, out, ws);
    capsule_logprob_reduce<<<1, 256, 0, stream>>>(ws, out);
    capsule_caps_pres<<<B_ * C_, 256, 0, stream>>>(vpp, out);
}

// Round 2
// 44.191 us; speedup vs baseline: 2.6125x; 2.6125x over previous
//
#include <hip/hip_runtime.h>

#define B_ 32
#define C_ 64
#define N_ 2048
#define D_ 6

static __device__ __forceinline__ float2 ld2(const float* p) {
    return *reinterpret_cast<const float2*>(p);
}

// Output layout (flat, return order), all float32
static constexpr long OFF_VP   = 1;
static constexpr long OFF_WIN  = OFF_VP   + (long)B_*C_*N_;
static constexpr long OFF_WINP = OFF_WIN  + (long)B_*N_*D_;
static constexpr long OFF_IFC  = OFF_WINP + (long)B_*N_;
static constexpr long OFF_ML   = OFF_IFC  + (long)B_*N_;
static constexpr long OFF_MLP  = OFF_ML   + (long)B_*(C_+1)*N_;
static constexpr long OFF_SW   = OFF_MLP  + (long)B_*(C_+1)*N_;
static constexpr long OFF_SWP  = OFF_SW   + (long)B_*N_*D_;
static constexpr long OFF_PMP  = OFF_SWP  + (long)B_*N_;
static constexpr long OFF_CAPS = OFF_PMP  + (long)B_*N_*C_;

// 4 waves per block, 64 points per block, wave `sub` handles capsules [16*sub, 16*sub+16)
#define CPS 16   // capsules per sub

__global__ __launch_bounds__(256) void capsule_main(
    const float* __restrict__ x,
    const float* __restrict__ votes,
    const float* __restrict__ scale,
    const float* __restrict__ vpp,
    const float* __restrict__ dummy_vote,
    float* __restrict__ out,
    float* __restrict__ block_sums)
{
    constexpr float DUMMY       = -4.6051702f;   // -2*ln(10)
    constexpr float HALFDLOG2PI =  5.5136312f;   // 0.5*D*ln(2*pi)

    const int tid  = threadIdx.x;
    const int lane = tid & 63;
    const int sub  = tid >> 6;                    // 0..3
    const int idx  = blockIdx.x * 64 + lane;      // b*N + n
    const int b    = idx >> 11;                   // N_ == 2048
    const int n    = idx & (N_ - 1);

    const float* xp = x + (size_t)idx * D_;
    const float2 xa = ld2(xp), xb = ld2(xp + 2), xc = ld2(xp + 4);

    const size_t base  = (size_t)b * (C_ * N_) + n;
    const size_t soff  = (size_t)(sub * CPS) * N_;
    const float* scp   = scale + base + soff;
    const float* ppp   = vpp   + base + soff;
    const float* vbs   = votes + (base + soff) * D_;
    const size_t mlrow = (size_t)b * ((C_ + 1) * N_) + n;

    float post[CPS], mlv[CPS];

    // sub 0 seeds the dummy contributions
    float s_pp = 0.0f, s_p = 0.0f;
    float sw0 = 0.f, sw1 = 0.f, sw2 = 0.f, sw3 = 0.f, sw4 = 0.f, sw5 = 0.f;
    if (sub == 0) {
        const float* dp = dummy_vote + (size_t)n * D_;
        const float2 da = ld2(dp), db = ld2(dp + 2), dc = ld2(dp + 4);
        s_pp = 0.01f;            // exp(DUMMY)
        s_p  = 1.0e-4f;          // exp(2*DUMMY)
        sw0 = 1.0e-4f * da.x; sw1 = 1.0e-4f * da.y;
        sw2 = 1.0e-4f * db.x; sw3 = 1.0e-4f * db.y;
        sw4 = 1.0e-4f * dc.x; sw5 = 1.0e-4f * dc.y;
    }
    float swp = 0.0f;
    float best = -3.4e38f, winp = 0.0f;
    float w0=0.f,w1=0.f,w2=0.f,w3=0.f,w4=0.f,w5=0.f;
    int bc = 0;

#pragma unroll
    for (int j = 0; j < CPS; ++j) {
        const int c = sub * CPS + j;
        const float* vp = vbs + (size_t)j * (N_ * D_);
        const float2 va = ld2(vp), vbb = ld2(vp + 2), vc2 = ld2(vp + 4);
        const float s = scp[(size_t)j * N_];
        const float p = ppp[(size_t)j * N_];
        const float inv = 1.0f / s;
        const float z0 = (xa.x - va.x)  * inv;
        const float z1 = (xa.y - va.y)  * inv;
        const float z2 = (xb.x - vbb.x) * inv;
        const float z3 = (xb.y - vbb.y) * inv;
        const float z4 = (xc.x - vc2.x) * inv;
        const float z5 = (xc.y - vc2.y) * inv;
        float q = z0 * z0;
        q = fmaf(z1, z1, q); q = fmaf(z2, z2, q);
        q = fmaf(z3, z3, q); q = fmaf(z4, z4, q);
        q = fmaf(z5, z5, q);
        const float vlp = fmaf(-0.5f, q, fmaf(-6.0f, __logf(s), -HALFDLOG2PI));
        const float ml  = __logf(p + 1e-16f);
        mlv[j] = ml;
        out[OFF_ML + mlrow + (size_t)c * N_] = ml;                          // coalesced over n
        out[OFF_VP + ((size_t)(b * C_ + c)) * N_ + n] = (DUMMY < ml) ? 1.0f : 0.0f;
        const float pc = ml + vlp;
        const float e  = __expf(pc);
        post[j] = e;
        s_pp += p + 1e-16f;
        s_p  += e;
        sw0 = fmaf(e, va.x,  sw0); sw1 = fmaf(e, va.y,  sw1);
        sw2 = fmaf(e, vbb.x, sw2); sw3 = fmaf(e, vbb.y, sw3);
        sw4 = fmaf(e, vc2.x, sw4); sw5 = fmaf(e, vc2.y, sw5);
        swp = fmaf(e, p, swp);
        const bool better = pc > best;                    // strict > keeps first occurrence
        best = better ? pc : best;
        bc   = better ? c  : bc;
        w0 = better ? va.x  : w0; w1 = better ? va.y  : w1;
        w2 = better ? vbb.x : w2; w3 = better ? vbb.y : w3;
        w4 = better ? vc2.x : w4; w5 = better ? vc2.y : w5;
        winp = better ? p : winp;
    }

    // ---- cross-sub combine via LDS ----
    // entries: 0 s_p | 1..6 sw | 7 swp | 8 s_pp | 9 best | 10..15 w | 16 winp
    __shared__ float lred[17 * 4 * 64];
    __shared__ int   lbc[4 * 64];
    __shared__ float lpmp[64 * 65];          // padded staging for transposed probs

#define LR(e) lred[(e) * 256 + sub * 64 + lane]
    LR(0) = s_p;
    LR(1) = sw0; LR(2) = sw1; LR(3) = sw2; LR(4) = sw3; LR(5) = sw4; LR(6) = sw5;
    LR(7) = swp; LR(8) = s_pp;
    LR(9) = best;
    LR(10) = w0; LR(11) = w1; LR(12) = w2; LR(13) = w3; LR(14) = w4; LR(15) = w5;
    LR(16) = winp;
    lbc[sub * 64 + lane] = bc;
#undef LR
    __syncthreads();

#define LS(e, s) lred[(e) * 256 + (s) * 64 + lane]
    float c_sp  = LS(0,0) + LS(0,1) + LS(0,2) + LS(0,3);
    float c_sw0 = LS(1,0) + LS(1,1) + LS(1,2) + LS(1,3);
    float c_sw1 = LS(2,0) + LS(2,1) + LS(2,2) + LS(2,3);
    float c_sw2 = LS(3,0) + LS(3,1) + LS(3,2) + LS(3,3);
    float c_sw3 = LS(4,0) + LS(4,1) + LS(4,2) + LS(4,3);
    float c_sw4 = LS(5,0) + LS(5,1) + LS(5,2) + LS(5,3);
    float c_sw5 = LS(6,0) + LS(6,1) + LS(6,2) + LS(6,3);
    float c_swp = LS(7,0) + LS(7,1) + LS(7,2) + LS(7,3);
    float c_spp = LS(8,0) + LS(8,1) + LS(8,2) + LS(8,3);
    float g_best = LS(9,0);
    int   g_bc   = lbc[lane];
    float g_w0 = LS(10,0), g_w1 = LS(11,0), g_w2 = LS(12,0),
          g_w3 = LS(13,0), g_w4 = LS(14,0), g_w5 = LS(15,0);
    float g_winp = LS(16,0);
#pragma unroll
    for (int s = 1; s < 4; ++s) {
        const float cb = LS(9, s);
        if (cb > g_best) {                      // strict >: earliest sub wins ties
            g_best = cb;
            g_bc   = lbc[s * 64 + lane];
            g_w0 = LS(10,s); g_w1 = LS(11,s); g_w2 = LS(12,s);
            g_w3 = LS(13,s); g_w4 = LS(14,s); g_w5 = LS(15,s);
            g_winp = LS(16,s);
        }
    }
#undef LS

    const float lse_ml = __logf(c_spp);
    const float lse_p  = __logf(c_sp);
    const float inv_sp = 1.0f / c_sp;

    if (sub == 0) {
        out[OFF_ML  + mlrow + (size_t)C_ * N_] = DUMMY;
        out[OFF_MLP + mlrow + (size_t)C_ * N_] = DUMMY - lse_ml;
        float* wq = out + OFF_WIN + (size_t)idx * D_;
        wq[0] = g_w0; wq[1] = g_w1; wq[2] = g_w2;
        wq[3] = g_w3; wq[4] = g_w4; wq[5] = g_w5;
        out[OFF_WINP + idx] = g_winp;
        out[OFF_IFC + idx]  = (float)(g_bc / N_);          // always 0
        float* sq = out + OFF_SW + (size_t)idx * D_;
        sq[0] = c_sw0 * inv_sp; sq[1] = c_sw1 * inv_sp; sq[2] = c_sw2 * inv_sp;
        sq[3] = c_sw3 * inv_sp; sq[4] = c_sw4 * inv_sp; sq[5] = c_sw5 * inv_sp;
        out[OFF_SWP + idx] = c_swp * inv_sp;
    }

    // mixing_log_prob for this sub's capsules (coalesced over n)
#pragma unroll
    for (int j = 0; j < CPS; ++j) {
        const int c = sub * CPS + j;
        out[OFF_MLP + mlrow + (size_t)c * N_] = mlv[j] - lse_ml;
    }

    // posterior_mixing_probs: stage in padded LDS, flush coalesced
#pragma unroll
    for (int j = 0; j < CPS; ++j)
        lpmp[lane * 65 + sub * CPS + j] = post[j] * inv_sp;
    __syncthreads();
    {
        const size_t pbase = OFF_PMP + (size_t)blockIdx.x * (64 * C_);
#pragma unroll
        for (int k = 0; k < 16; ++k) {
            const int g = tid + k * 256;
            const int p = g >> 6, cc = g & 63;
            out[pbase + g] = lpmp[p * 65 + cc];
        }
    }

    // deterministic per-block sum of lse_p (one value per point, wave 0 only)
    if (sub == 0) {
        float v = lse_p;
#pragma unroll
        for (int m = 32; m > 0; m >>= 1)
            v += __shfl_xor(v, m, 64);
        if (lane == 0) block_sums[blockIdx.x] = v;
    }
}

__global__ __launch_bounds__(256) void capsule_logprob_reduce(
    const float* __restrict__ block_sums, float* __restrict__ out)
{
    __shared__ float red[256];
    const int tid = threadIdx.x;
    red[tid] = block_sums[tid] + block_sums[tid + 256]
             + block_sums[tid + 512] + block_sums[tid + 768];
    __syncthreads();
#pragma unroll
    for (int off2 = 128; off2 > 0; off2 >>= 1) {
        if (tid < off2) red[tid] += red[tid + off2];
        __syncthreads();
    }
    if (tid == 0) out[0] = red[0] * (1.0f / (float)B_);
}

__global__ __launch_bounds__(256) void capsule_caps_pres(
    const float* __restrict__ vpp, float* __restrict__ out)
{
    const int bcq = blockIdx.x;             // b*C + c
    const int tid = threadIdx.x;
    const float* p = vpp + (size_t)bcq * N_;
    float m = -3.4e38f;
#pragma unroll
    for (int t = 0; t < N_ / 256; ++t)
        m = fmaxf(m, p[t * 256 + tid]);
    __shared__ float red[256];
    red[tid] = m;
    __syncthreads();
#pragma unroll
    for (int off2 = 128; off2 > 0; off2 >>= 1) {
        if (tid < off2) red[tid] = fmaxf(red[tid], red[tid + off2]);
        __syncthreads();
    }
    if (tid == 0) out[OFF_CAPS + bcq] = red[0];
}

extern "C" void kernel_launch(void* const* d_in, const int* in_sizes, int n_in,
                              void* d_out, int out_size, void* d_ws, size_t ws_size,
                              hipStream_t stream) {
    const float* x     = (const float*)d_in[0];
    const float* votes = (const float*)d_in[1];
    const float* scale = (const float*)d_in[2];
    const float* vpp   = (const float*)d_in[3];
    const float* dummy = (const float*)d_in[4];
    float* out = (float*)d_out;
    float* ws  = (float*)d_ws;   // 1024 floats of block sums

    capsule_main<<<(B_ * N_) / 64, 256, 0, stream>>>(x, votes, scale, vpp, dummy, out, ws);
    capsule_logprob_reduce<<<1, 256, 0, stream>>>(ws, out);
    capsule_caps_pres<<<B_ * C_, 256, 0, stream>>>(vpp, out);
}